// Round 2
// baseline (2225.212 us; speedup 1.0000x reference)
//
#include <hip/hip_runtime.h>

#define T_   16
#define B_   8
#define N_   8
#define H_   128
#define C_   32
#define HW_  256
#define TAR_ 145
#define G4H  512
#define MEMIN 8593

__device__ __forceinline__ float bf2f(unsigned short u){
  return __uint_as_float(((unsigned int)u) << 16);
}
__device__ __forceinline__ unsigned short f2bf(float x){
  unsigned int b = __float_as_uint(x);
  return (unsigned short)((b + 0x7fffu + ((b >> 16) & 1u)) >> 16);
}

// ---------------------------------------------------------------------------
// shared[h] = Wo_b[h] + sum_d Wv_b[d] * Wo_w[h,d]
// (attention collapses: keys==0 -> all v identical -> uniform softmax)
// ---------------------------------------------------------------------------
__global__ void k_shared(const float* __restrict__ WvB, const float* __restrict__ WoW,
                         const float* __restrict__ WoB, float* __restrict__ sh){
  const int h = blockIdx.x, lane = threadIdx.x;
  float acc = 0.f;
  for(int d = lane; d < 896; d += 64) acc += WvB[d] * WoW[h*896 + d];
  for(int s = 32; s; s >>= 1) acc += __shfl_down(acc, s);
  if(lane == 0) sh[h] = acc + WoB[h];
}

// ---------------------------------------------------------------------------
// gate[tb,n,c] = sigmoid(td_b[n,c] + sum_{x<145} tar[tb,x]*td_w[n,c,x])
// (ctx[...,145:] == 0 since prev_h == 0)
// ---------------------------------------------------------------------------
__global__ __launch_bounds__(256) void k_gate(const float* __restrict__ tar,
                                              const float* __restrict__ tdw,
                                              const float* __restrict__ tdb,
                                              float* __restrict__ gate){
  __shared__ float twS[32*145];
  __shared__ float taS[16*145];
  const int tb0 = blockIdx.x * 16, n = blockIdx.y, tid = threadIdx.x;
  for(int i = tid; i < 32*145; i += 256){
    int c = i / 145, x = i - c*145;
    twS[i] = tdw[(n*32 + c)*273 + x];
  }
  for(int i = tid; i < 16*145; i += 256)
    taS[i] = tar[tb0*145 + i];
  __syncthreads();
  for(int o = tid; o < 512; o += 256){
    int r = o >> 5, c = o & 31;
    float a = tdb[n*32 + c];
    const float* tr = &taS[r*145];
    const float* tw = &twS[c*145];
    for(int x = 0; x < 145; ++x) a += tr[x]*tw[x];
    gate[((tb0 + r)*N_ + n)*C_ + c] = 1.f/(1.f + expf(-a));
  }
}

// ---------------------------------------------------------------------------
// xg[tb,n,g] = bih+bhh + sum_k mem[tb,n,k]*Wih[n,g,k], mem generated on the fly:
//   k in [0,8192)    : conv_b[d] + sum_c conv_w[d,c]*gate[tb,n,c]*img[tb,c,hw]
//   k in [8192,8320) : shared[k-8192]           (row-independent)
//   k in [8320,8465) : tar[tb,k-8320]
//   k in [8465,8593) : 0  (never read)
// Block: n x (128 g) x (16 tb rows); thread tile 2 rows x 4 g.
// ---------------------------------------------------------------------------
__global__ __launch_bounds__(256) void k_gemm(
    const float* __restrict__ img, const float* __restrict__ gate,
    const float* __restrict__ cw, const float* __restrict__ cb,
    const float* __restrict__ sh, const float* __restrict__ tar,
    const float* __restrict__ Wih, const float* __restrict__ bih,
    const float* __restrict__ bhh, float* __restrict__ xg)
{
  __shared__ __align__(16) float imgS[16*545];   // [r][c][j] strides 545/17/1
  __shared__ __align__(16) float WtS[16*132];    // [j][g] pad 132
  __shared__ float PS[16*17];                    // [j][r]
  __shared__ float gateS[16*32];
  __shared__ float cw2S[16*32];
  __shared__ float cwS[32*32];
  __shared__ float cbS[32];
  __shared__ float shS[128];
  __shared__ float tarS[16*145];

  const int tid = threadIdx.x;
  const int g0  = blockIdx.x * 128;
  const int tb0 = blockIdx.y * 16;
  const int n   = blockIdx.z;
  const int gth = tid & 31;   // 32 groups * 4 g
  const int rth = tid >> 5;   // 8 groups * 2 rows
  const long wbase = (long)(n*G4H + g0) * MEMIN;

  for(int i = tid; i < 16*32; i += 256){
    int r = i >> 5, c = i & 31;
    gateS[i] = gate[((tb0 + r)*N_ + n)*C_ + c];
  }
  for(int i = tid; i < 32*32; i += 256) cwS[i] = cw[i];
  if(tid < 32)  cbS[tid] = cb[tid];
  if(tid < 128) shS[tid] = sh[tid];
  for(int i = tid; i < 16*TAR_; i += 256)
    tarS[i] = tar[tb0*TAR_ + i];

  float acc0[4] = {0,0,0,0}, acc1[4] = {0,0,0,0};

  // -------- conv region --------
  for(int s = 0; s < 16; ++s){
    __syncthreads();
    for(int i = tid; i < 8192; i += 256){
      int j = i & 15, c = (i >> 4) & 31, r = i >> 9;
      imgS[r*545 + c*17 + j] = img[((tb0 + r)*C_ + c)*HW_ + s*16 + j];
    }
    for(int d = 0; d < 32; ++d){
      __syncthreads();
      for(int i = tid; i < 2048; i += 256){
        int g = i >> 4, j = i & 15;
        WtS[j*132 + g] = Wih[wbase + (long)g*MEMIN + d*HW_ + s*16 + j];
      }
      for(int i = tid; i < 512; i += 256)
        cw2S[i] = gateS[i] * cwS[d*32 + (i & 31)];
      __syncthreads();
      {
        int j = tid & 15, r = tid >> 4;
        float a = cbS[d];
        const float* c2 = &cw2S[r*32];
        const float* im = &imgS[r*545 + j];
        #pragma unroll
        for(int c = 0; c < 32; ++c) a += c2[c] * im[c*17];
        PS[j*17 + r] = a;
      }
      __syncthreads();
      #pragma unroll
      for(int j = 0; j < 16; ++j){
        const float4 w = *(const float4*)&WtS[j*132 + (gth << 2)];
        const float p0 = PS[j*17 + (rth << 1)];
        const float p1 = PS[j*17 + (rth << 1) + 1];
        acc0[0] += p0*w.x; acc0[1] += p0*w.y; acc0[2] += p0*w.z; acc0[3] += p0*w.w;
        acc1[0] += p1*w.x; acc1[1] += p1*w.y; acc1[2] += p1*w.z; acc1[3] += p1*w.w;
      }
    }
  }

  // -------- shared region (same contribution for every row) --------
  {
    float ta[4] = {0,0,0,0};
    for(int kc = 0; kc < 8; ++kc){
      __syncthreads();
      for(int i = tid; i < 2048; i += 256){
        int g = i >> 4, j = i & 15;
        WtS[j*132 + g] = Wih[wbase + (long)g*MEMIN + 8192 + kc*16 + j];
      }
      __syncthreads();
      #pragma unroll
      for(int j = 0; j < 16; ++j){
        const float4 w = *(const float4*)&WtS[j*132 + (gth << 2)];
        const float sv = shS[kc*16 + j];
        ta[0] += sv*w.x; ta[1] += sv*w.y; ta[2] += sv*w.z; ta[3] += sv*w.w;
      }
    }
    acc0[0] += ta[0]; acc0[1] += ta[1]; acc0[2] += ta[2]; acc0[3] += ta[3];
    acc1[0] += ta[0]; acc1[1] += ta[1]; acc1[2] += ta[2]; acc1[3] += ta[3];
  }

  // -------- tar region (145 = 9*16 + 1) --------
  for(int kc = 0; kc < 10; ++kc){
    const int kend = (kc == 9) ? 1 : 16;
    __syncthreads();
    for(int i = tid; i < 2048; i += 256){
      int g = i >> 4, j = i & 15;
      if(j < kend)
        WtS[j*132 + g] = Wih[wbase + (long)g*MEMIN + 8320 + kc*16 + j];
    }
    __syncthreads();
    for(int j = 0; j < kend; ++j){
      const float4 w = *(const float4*)&WtS[j*132 + (gth << 2)];
      const float p0 = tarS[(rth << 1)*TAR_ + kc*16 + j];
      const float p1 = tarS[((rth << 1) + 1)*TAR_ + kc*16 + j];
      acc0[0] += p0*w.x; acc0[1] += p0*w.y; acc0[2] += p0*w.z; acc0[3] += p0*w.w;
      acc1[0] += p1*w.x; acc1[1] += p1*w.y; acc1[2] += p1*w.z; acc1[3] += p1*w.w;
    }
  }

  // -------- epilogue --------
  {
    const int gg = g0 + (gth << 2);
    const float b0 = bih[n*G4H + gg + 0] + bhh[n*G4H + gg + 0];
    const float b1 = bih[n*G4H + gg + 1] + bhh[n*G4H + gg + 1];
    const float b2 = bih[n*G4H + gg + 2] + bhh[n*G4H + gg + 2];
    const float b3 = bih[n*G4H + gg + 3] + bhh[n*G4H + gg + 3];
    const int row = tb0 + (rth << 1);
    float4 o0 = make_float4(acc0[0]+b0, acc0[1]+b1, acc0[2]+b2, acc0[3]+b3);
    *(float4*)&xg[((long)(row*N_ + n))*G4H + gg] = o0;
    float4 o1 = make_float4(acc1[0]+b0, acc1[1]+b1, acc1[2]+b2, acc1[3]+b3);
    *(float4*)&xg[((long)((row + 1)*N_ + n))*G4H + gg] = o1;
  }
}

// ---------------------------------------------------------------------------
// Per-schema LSTM over 16 steps. One block per n (schemas independent).
// Whh[n] staged once as bf16 in (dynamic) LDS; thread = (b, h).
// Output is FLOAT32 (reference returns f32 arrays).
// ---------------------------------------------------------------------------
__global__ __launch_bounds__(1024) void k_lstm(
    const float* __restrict__ xg, const float* __restrict__ Whh,
    float* __restrict__ out)
{
  extern __shared__ char smem[];
  unsigned short* Wl = (unsigned short*)smem;                       // [512][136]
  float* hS = (float*)(smem + 512*136*sizeof(unsigned short));      // [8][128]

  const int n = blockIdx.x, tid = threadIdx.x;
  for(int i = tid; i < 512*128; i += 1024){
    int g = i >> 7, k = i & 127;
    Wl[g*136 + k] = f2bf(Whh[n*512*128 + i]);
  }
  hS[tid] = 0.f;
  const int h = tid >> 3, b = tid & 7;
  float cc = 0.f;
  __syncthreads();

  for(int t = 0; t < 16; ++t){
    const long xbase = ((long)((t*8 + b)*8 + n))*G4H + h;
    float g0 = xg[xbase + 0*128];
    float g1 = xg[xbase + 1*128];
    float g2 = xg[xbase + 2*128];
    float g3 = xg[xbase + 3*128];
    const float* hr = &hS[b*128];
    const unsigned short* w0 = &Wl[(0*128 + h)*136];
    const unsigned short* w1 = &Wl[(1*128 + h)*136];
    const unsigned short* w2 = &Wl[(2*128 + h)*136];
    const unsigned short* w3 = &Wl[(3*128 + h)*136];
    for(int k = 0; k < 128; k += 4){
      const float4 hv = *(const float4*)&hr[k];
      const ushort4 a0 = *(const ushort4*)&w0[k];
      const ushort4 a1 = *(const ushort4*)&w1[k];
      const ushort4 a2 = *(const ushort4*)&w2[k];
      const ushort4 a3 = *(const ushort4*)&w3[k];
      g0 += hv.x*bf2f(a0.x) + hv.y*bf2f(a0.y) + hv.z*bf2f(a0.z) + hv.w*bf2f(a0.w);
      g1 += hv.x*bf2f(a1.x) + hv.y*bf2f(a1.y) + hv.z*bf2f(a1.z) + hv.w*bf2f(a1.w);
      g2 += hv.x*bf2f(a2.x) + hv.y*bf2f(a2.y) + hv.z*bf2f(a2.z) + hv.w*bf2f(a2.w);
      g3 += hv.x*bf2f(a3.x) + hv.y*bf2f(a3.y) + hv.z*bf2f(a3.z) + hv.w*bf2f(a3.w);
    }
    const float iv = 1.f/(1.f + expf(-g0));
    const float fv = 1.f/(1.f + expf(-g1));
    const float gv = tanhf(g2);
    const float ov = 1.f/(1.f + expf(-g3));
    cc = fv*cc + iv*gv;
    const float hn = ov * tanhf(cc);
    __syncthreads();
    hS[b*128 + h] = hn;
    out[(t*8 + b)*1024 + n*128 + h] = hn;
    if(t == 15){
      out[131072 + (b*8 + n)*128 + h] = hn;   // hT
      out[139264 + (b*8 + n)*128 + h] = cc;   // cT
    }
    __syncthreads();
  }
}

// ---------------------------------------------------------------------------
extern "C" void kernel_launch(void* const* d_in, const int* in_sizes, int n_in,
                              void* d_out, int out_size, void* d_ws, size_t ws_size,
                              hipStream_t stream)
{
  (void)in_sizes; (void)n_in; (void)out_size; (void)ws_size;
  const float* img  = (const float*)d_in[0];
  const float* tar  = (const float*)d_in[1];
  // d_in[2..6] (Wq_w, Wq_b, Wk_w, Wk_b, Wv_w) are structurally dead (keys==0)
  const float* WvB  = (const float*)d_in[7];
  const float* WoW  = (const float*)d_in[8];
  const float* WoB  = (const float*)d_in[9];
  const float* tdw  = (const float*)d_in[10];
  const float* tdb  = (const float*)d_in[11];
  const float* cw   = (const float*)d_in[12];
  const float* cb   = (const float*)d_in[13];
  const float* Wih  = (const float*)d_in[14];
  const float* Whh  = (const float*)d_in[15];
  const float* bih  = (const float*)d_in[16];
  const float* bhh  = (const float*)d_in[17];

  float* wsf   = (float*)d_ws;
  float* gatew = wsf;           // 32768 floats
  float* shw   = wsf + 32768;   // 128 floats
  float* xgw   = wsf + 32896;   // 524288 floats  (total ws use ~2.23 MB)

  k_shared<<<128, 64, 0, stream>>>(WvB, WoW, WoB, shw);
  k_gate<<<dim3(8, 8), 256, 0, stream>>>(tar, tdw, tdb, gatew);
  k_gemm<<<dim3(4, 8, 8), 256, 0, stream>>>(img, gatew, cw, cb, shw, tar,
                                            Wih, bih, bhh, xgw);
  (void)hipFuncSetAttribute((const void*)k_lstm,
                            hipFuncAttributeMaxDynamicSharedMemorySize, 143360);
  k_lstm<<<8, 1024, 143360, stream>>>(xgw, Whh, (float*)d_out);
}

// Round 3
// 334.160 us; speedup vs baseline: 6.6591x; 6.6591x over previous
//
#include <hip/hip_runtime.h>

#define T_   16
#define B_   8
#define N_   8
#define H_   128
#define C_   32
#define HW_  256
#define TAR_ 145
#define G4H  512
#define MEMIN 8593
#define AK   8480   // padded K for MFMA path: 8192 conv + 128 shared + 145 tar + 15 zero

typedef __attribute__((ext_vector_type(8))) short short8v;
typedef __attribute__((ext_vector_type(4))) float f32x4;
typedef __attribute__((ext_vector_type(4), aligned(4))) float f32x4u; // 4B-aligned vec load

__device__ __forceinline__ float bf2f(unsigned short u){
  return __uint_as_float(((unsigned int)u) << 16);
}
__device__ __forceinline__ unsigned short f2bf(float x){
  unsigned int b = __float_as_uint(x);
  return (unsigned short)((b + 0x7fffu + ((b >> 16) & 1u)) >> 16);
}

// ---------------------------------------------------------------------------
// shared[h] = Wo_b[h] + sum_d Wv_b[d] * Wo_w[h,d]   (attention collapses)
// ---------------------------------------------------------------------------
__global__ void k_shared(const float* __restrict__ WvB, const float* __restrict__ WoW,
                         const float* __restrict__ WoB, float* __restrict__ sh){
  const int h = blockIdx.x, lane = threadIdx.x;
  float acc = 0.f;
  for(int d = lane; d < 896; d += 64) acc += WvB[d] * WoW[h*896 + d];
  for(int s = 32; s; s >>= 1) acc += __shfl_down(acc, s);
  if(lane == 0) sh[h] = acc + WoB[h];
}

// ---------------------------------------------------------------------------
// gate[tb,n,c] = sigmoid(td_b[n,c] + sum_{x<145} tar[tb,x]*td_w[n,c,x])
// ---------------------------------------------------------------------------
__global__ __launch_bounds__(256) void k_gate(const float* __restrict__ tar,
                                              const float* __restrict__ tdw,
                                              const float* __restrict__ tdb,
                                              float* __restrict__ gate){
  __shared__ float twS[32*145];
  __shared__ float taS[16*145];
  const int tb0 = blockIdx.x * 16, n = blockIdx.y, tid = threadIdx.x;
  for(int i = tid; i < 32*145; i += 256){
    int c = i / 145, x = i - c*145;
    twS[i] = tdw[(n*32 + c)*273 + x];
  }
  for(int i = tid; i < 16*145; i += 256)
    taS[i] = tar[tb0*145 + i];
  __syncthreads();
  for(int o = tid; o < 512; o += 256){
    int r = o >> 5, c = o & 31;
    float a = tdb[n*32 + c];
    const float* tr = &taS[r*145];
    const float* tw = &twS[c*145];
    for(int x = 0; x < 145; ++x) a += tr[x]*tw[x];
    gate[((tb0 + r)*N_ + n)*C_ + c] = 1.f/(1.f + expf(-a));
  }
}

// ---------------------------------------------------------------------------
// Build mem_bf16[n][tb][AK]: [0,8192) conv P, [8192,8320) shared,
// [8320,8465) tar, [8465,8480) zeros.  One block per tb; img staged once.
// ---------------------------------------------------------------------------
__global__ __launch_bounds__(512) void k_conv(
    const float* __restrict__ img, const float* __restrict__ gate,
    const float* __restrict__ cw, const float* __restrict__ cb,
    const float* __restrict__ sh, const float* __restrict__ tar,
    unsigned short* __restrict__ mem)
{
  __shared__ float imgS[8192];
  __shared__ float cwgS[1024];
  __shared__ float shS[128];
  __shared__ float tarS[160];
  const int tb = blockIdx.x, tid = threadIdx.x;
  for(int i = tid; i < 8192; i += 512)
    imgS[i] = img[(size_t)tb*8192 + i];
  if(tid < 128) shS[tid] = sh[tid];
  if(tid >= 128 && tid < 273) tarS[tid-128] = tar[tb*TAR_ + tid - 128];
  for(int n = 0; n < 8; ++n){
    __syncthreads();   // imgS ready (n=0) / previous n's readers done
    for(int i = tid; i < 1024; i += 512)
      cwgS[i] = cw[i] * gate[(tb*8 + n)*32 + (i & 31)];
    __syncthreads();
    unsigned short* mrow = mem + (size_t)(n*128 + tb)*AK;
    for(int q = 0; q < 4; ++q){
      const int idx = q*2048 + tid*4;
      const int d = idx >> 8, hw = idx & 255;
      const float bias = cb[d];
      float a0 = bias, a1 = bias, a2 = bias, a3 = bias;
      const float* cg = &cwgS[d*32];
      #pragma unroll
      for(int c = 0; c < 32; ++c){
        const f32x4 iv = *(const f32x4*)&imgS[c*256 + hw];
        const float w = cg[c];
        a0 += w*iv.x; a1 += w*iv.y; a2 += w*iv.z; a3 += w*iv.w;
      }
      ushort4 o;
      o.x = f2bf(a0); o.y = f2bf(a1); o.z = f2bf(a2); o.w = f2bf(a3);
      *(ushort4*)&mrow[idx] = o;
    }
    if(tid < 128)      mrow[8192 + tid]       = f2bf(shS[tid]);
    else if(tid < 273) mrow[8320 + tid - 128] = f2bf(tarS[tid - 128]);
    else if(tid < 288) mrow[8465 + tid - 273] = 0;
  }
}

// ---------------------------------------------------------------------------
// xg[i] = bih + bhh (pre-bias; k_gemm_mfma atomically accumulates on top)
// ---------------------------------------------------------------------------
__global__ __launch_bounds__(256) void k_bias(const float* __restrict__ bih,
                                              const float* __restrict__ bhh,
                                              float* __restrict__ xg){
  const int i = blockIdx.x*256 + threadIdx.x;          // 524288 total
  const int ng = ((i >> 9) & 7)*512 + (i & 511);
  xg[i] = bih[ng] + bhh[ng];
}

// ---------------------------------------------------------------------------
// Barrier-free MFMA GEMM: per n, C[128 tb x 512 g] += mem_bf16 . Wih^T.
// Block = 4 waves; wave owns 32 rows x 16 g; K streamed directly from global
// (A bf16 16B/lane, B f32 32B/lane -> cvt). k-slot placement identical for
// A and B => invariant to HW k-ordering. C/D: col=lane&15,row=(lane>>4)*4+j.
// ---------------------------------------------------------------------------
__global__ __launch_bounds__(256) void k_gemm_mfma(
    const unsigned short* __restrict__ mem, const float* __restrict__ Wih,
    float* __restrict__ xg)
{
  const int gt = blockIdx.x, n = blockIdx.y, ks = blockIdx.z;
  const int wv = threadIdx.x >> 6, ln = threadIdx.x & 63;
  const int lr = ln & 15, lg = ln >> 4;
  const int g0 = gt*16;
  const int kbeg = (ks==0) ? 0 : (ks==1) ? 2144 : (ks==2) ? 4256 : 6368;
  const int kend = (ks==0) ? 2144 : (ks==1) ? 4256 : (ks==2) ? 6368 : 8480;
  const float* Bp = Wih + (size_t)(n*G4H + g0 + lr)*MEMIN + lg*8;
  const unsigned short* Ap = mem + (size_t)(n*128 + wv*32 + lr)*AK + lg*8;
  f32x4 acc0 = {0.f,0.f,0.f,0.f};
  f32x4 acc1 = {0.f,0.f,0.f,0.f};
  #pragma unroll 2
  for(int k = kbeg; k < kend; k += 32){
    const f32x4u blo = *(const f32x4u*)(Bp + k);
    const f32x4u bhi = *(const f32x4u*)(Bp + k + 4);
    short8v bf;
    bf[0] = (short)f2bf(blo.x); bf[1] = (short)f2bf(blo.y);
    bf[2] = (short)f2bf(blo.z); bf[3] = (short)f2bf(blo.w);
    bf[4] = (short)f2bf(bhi.x); bf[5] = (short)f2bf(bhi.y);
    bf[6] = (short)f2bf(bhi.z); bf[7] = (short)f2bf(bhi.w);
    const short8v a0 = *(const short8v*)(Ap + k);
    const short8v a1 = *(const short8v*)(Ap + (size_t)16*AK + k);
    acc0 = __builtin_amdgcn_mfma_f32_16x16x32_bf16(a0, bf, acc0, 0, 0, 0);
    acc1 = __builtin_amdgcn_mfma_f32_16x16x32_bf16(a1, bf, acc1, 0, 0, 0);
  }
  const int col = g0 + lr;
  const int r0  = wv*32 + lg*4;
  #pragma unroll
  for(int j = 0; j < 4; ++j){
    atomicAdd(&xg[(size_t)((r0 + j)*8 + n)*G4H + col],      acc0[j]);
    atomicAdd(&xg[(size_t)((r0 + 16 + j)*8 + n)*G4H + col], acc1[j]);
  }
}

// ---------------------------------------------------------------------------
// Fallback GEMM (round-2 verified path) used only if ws_size is too small.
// ---------------------------------------------------------------------------
__global__ __launch_bounds__(256) void k_gemm_old(
    const float* __restrict__ img, const float* __restrict__ gate,
    const float* __restrict__ cw, const float* __restrict__ cb,
    const float* __restrict__ sh, const float* __restrict__ tar,
    const float* __restrict__ Wih, const float* __restrict__ bih,
    const float* __restrict__ bhh, float* __restrict__ xg)
{
  __shared__ __align__(16) float imgS[16*545];
  __shared__ __align__(16) float WtS[16*132];
  __shared__ float PS[16*17];
  __shared__ float gateS[16*32];
  __shared__ float cw2S[16*32];
  __shared__ float cwS[32*32];
  __shared__ float cbS[32];
  __shared__ float shS[128];
  __shared__ float tarS[16*145];

  const int tid = threadIdx.x;
  const int g0  = blockIdx.x * 128;
  const int tb0 = blockIdx.y * 16;
  const int n   = blockIdx.z;
  const int gth = tid & 31;
  const int rth = tid >> 5;
  const long wbase = (long)(n*G4H + g0) * MEMIN;

  for(int i = tid; i < 16*32; i += 256){
    int r = i >> 5, c = i & 31;
    gateS[i] = gate[((tb0 + r)*N_ + n)*C_ + c];
  }
  for(int i = tid; i < 32*32; i += 256) cwS[i] = cw[i];
  if(tid < 32)  cbS[tid] = cb[tid];
  if(tid < 128) shS[tid] = sh[tid];
  for(int i = tid; i < 16*TAR_; i += 256)
    tarS[i] = tar[tb0*TAR_ + i];

  float acc0[4] = {0,0,0,0}, acc1[4] = {0,0,0,0};

  for(int s = 0; s < 16; ++s){
    __syncthreads();
    for(int i = tid; i < 8192; i += 256){
      int j = i & 15, c = (i >> 4) & 31, r = i >> 9;
      imgS[r*545 + c*17 + j] = img[((tb0 + r)*C_ + c)*HW_ + s*16 + j];
    }
    for(int d = 0; d < 32; ++d){
      __syncthreads();
      for(int i = tid; i < 2048; i += 256){
        int g = i >> 4, j = i & 15;
        WtS[j*132 + g] = Wih[wbase + (long)g*MEMIN + d*HW_ + s*16 + j];
      }
      for(int i = tid; i < 512; i += 256)
        cw2S[i] = gateS[i] * cwS[d*32 + (i & 31)];
      __syncthreads();
      {
        int j = tid & 15, r = tid >> 4;
        float a = cbS[d];
        const float* c2 = &cw2S[r*32];
        const float* im = &imgS[r*545 + j];
        #pragma unroll
        for(int c = 0; c < 32; ++c) a += c2[c] * im[c*17];
        PS[j*17 + r] = a;
      }
      __syncthreads();
      #pragma unroll
      for(int j = 0; j < 16; ++j){
        const float4 w = *(const float4*)&WtS[j*132 + (gth << 2)];
        const float p0 = PS[j*17 + (rth << 1)];
        const float p1 = PS[j*17 + (rth << 1) + 1];
        acc0[0] += p0*w.x; acc0[1] += p0*w.y; acc0[2] += p0*w.z; acc0[3] += p0*w.w;
        acc1[0] += p1*w.x; acc1[1] += p1*w.y; acc1[2] += p1*w.z; acc1[3] += p1*w.w;
      }
    }
  }
  {
    float ta[4] = {0,0,0,0};
    for(int kc = 0; kc < 8; ++kc){
      __syncthreads();
      for(int i = tid; i < 2048; i += 256){
        int g = i >> 4, j = i & 15;
        WtS[j*132 + g] = Wih[wbase + (long)g*MEMIN + 8192 + kc*16 + j];
      }
      __syncthreads();
      #pragma unroll
      for(int j = 0; j < 16; ++j){
        const float4 w = *(const float4*)&WtS[j*132 + (gth << 2)];
        const float sv = shS[kc*16 + j];
        ta[0] += sv*w.x; ta[1] += sv*w.y; ta[2] += sv*w.z; ta[3] += sv*w.w;
      }
    }
    acc0[0] += ta[0]; acc0[1] += ta[1]; acc0[2] += ta[2]; acc0[3] += ta[3];
    acc1[0] += ta[0]; acc1[1] += ta[1]; acc1[2] += ta[2]; acc1[3] += ta[3];
  }
  for(int kc = 0; kc < 10; ++kc){
    const int kendl = (kc == 9) ? 1 : 16;
    __syncthreads();
    for(int i = tid; i < 2048; i += 256){
      int g = i >> 4, j = i & 15;
      if(j < kendl)
        WtS[j*132 + g] = Wih[wbase + (long)g*MEMIN + 8320 + kc*16 + j];
    }
    __syncthreads();
    for(int j = 0; j < kendl; ++j){
      const float4 w = *(const float4*)&WtS[j*132 + (gth << 2)];
      const float p0 = tarS[(rth << 1)*TAR_ + kc*16 + j];
      const float p1 = tarS[((rth << 1) + 1)*TAR_ + kc*16 + j];
      acc0[0] += p0*w.x; acc0[1] += p0*w.y; acc0[2] += p0*w.z; acc0[3] += p0*w.w;
      acc1[0] += p1*w.x; acc1[1] += p1*w.y; acc1[2] += p1*w.z; acc1[3] += p1*w.w;
    }
  }
  {
    const int gg = g0 + (gth << 2);
    const float b0 = bih[n*G4H + gg + 0] + bhh[n*G4H + gg + 0];
    const float b1 = bih[n*G4H + gg + 1] + bhh[n*G4H + gg + 1];
    const float b2 = bih[n*G4H + gg + 2] + bhh[n*G4H + gg + 2];
    const float b3 = bih[n*G4H + gg + 3] + bhh[n*G4H + gg + 3];
    const int row = tb0 + (rth << 1);
    float4 o0 = make_float4(acc0[0]+b0, acc0[1]+b1, acc0[2]+b2, acc0[3]+b3);
    *(float4*)&xg[((long)(row*N_ + n))*G4H + gg] = o0;
    float4 o1 = make_float4(acc1[0]+b0, acc1[1]+b1, acc1[2]+b2, acc1[3]+b3);
    *(float4*)&xg[((long)((row + 1)*N_ + n))*G4H + gg] = o1;
  }
}

// ---------------------------------------------------------------------------
// Per-schema LSTM, one block per n. Whh staged bf16 in dynamic LDS.
// ---------------------------------------------------------------------------
__global__ __launch_bounds__(1024) void k_lstm(
    const float* __restrict__ xg, const float* __restrict__ Whh,
    float* __restrict__ out)
{
  extern __shared__ char smem[];
  unsigned short* Wl = (unsigned short*)smem;                       // [512][136]
  float* hS = (float*)(smem + 512*136*sizeof(unsigned short));      // [8][128]

  const int n = blockIdx.x, tid = threadIdx.x;
  for(int i = tid; i < 512*128; i += 1024){
    int g = i >> 7, k = i & 127;
    Wl[g*136 + k] = f2bf(Whh[n*512*128 + i]);
  }
  hS[tid] = 0.f;
  const int h = tid >> 3, b = tid & 7;
  float cc = 0.f;
  __syncthreads();

  for(int t = 0; t < 16; ++t){
    const long xbase = ((long)((t*8 + b)*8 + n))*G4H + h;
    float g0 = xg[xbase + 0*128];
    float g1 = xg[xbase + 1*128];
    float g2 = xg[xbase + 2*128];
    float g3 = xg[xbase + 3*128];
    const float* hr = &hS[b*128];
    const unsigned short* w0 = &Wl[(0*128 + h)*136];
    const unsigned short* w1 = &Wl[(1*128 + h)*136];
    const unsigned short* w2 = &Wl[(2*128 + h)*136];
    const unsigned short* w3 = &Wl[(3*128 + h)*136];
    for(int k = 0; k < 128; k += 4){
      const float4 hv = *(const float4*)&hr[k];
      const ushort4 a0 = *(const ushort4*)&w0[k];
      const ushort4 a1 = *(const ushort4*)&w1[k];
      const ushort4 a2 = *(const ushort4*)&w2[k];
      const ushort4 a3 = *(const ushort4*)&w3[k];
      g0 += hv.x*bf2f(a0.x) + hv.y*bf2f(a0.y) + hv.z*bf2f(a0.z) + hv.w*bf2f(a0.w);
      g1 += hv.x*bf2f(a1.x) + hv.y*bf2f(a1.y) + hv.z*bf2f(a1.z) + hv.w*bf2f(a1.w);
      g2 += hv.x*bf2f(a2.x) + hv.y*bf2f(a2.y) + hv.z*bf2f(a2.z) + hv.w*bf2f(a2.w);
      g3 += hv.x*bf2f(a3.x) + hv.y*bf2f(a3.y) + hv.z*bf2f(a3.z) + hv.w*bf2f(a3.w);
    }
    const float iv = 1.f/(1.f + expf(-g0));
    const float fv = 1.f/(1.f + expf(-g1));
    const float gv = tanhf(g2);
    const float ov = 1.f/(1.f + expf(-g3));
    cc = fv*cc + iv*gv;
    const float hn = ov * tanhf(cc);
    __syncthreads();
    hS[b*128 + h] = hn;
    out[(t*8 + b)*1024 + n*128 + h] = hn;
    if(t == 15){
      out[131072 + (b*8 + n)*128 + h] = hn;   // hT
      out[139264 + (b*8 + n)*128 + h] = cc;   // cT
    }
    __syncthreads();
  }
}

// ---------------------------------------------------------------------------
extern "C" void kernel_launch(void* const* d_in, const int* in_sizes, int n_in,
                              void* d_out, int out_size, void* d_ws, size_t ws_size,
                              hipStream_t stream)
{
  (void)in_sizes; (void)n_in; (void)out_size;
  const float* img  = (const float*)d_in[0];
  const float* tar  = (const float*)d_in[1];
  const float* WvB  = (const float*)d_in[7];
  const float* WoW  = (const float*)d_in[8];
  const float* WoB  = (const float*)d_in[9];
  const float* tdw  = (const float*)d_in[10];
  const float* tdb  = (const float*)d_in[11];
  const float* cw   = (const float*)d_in[12];
  const float* cb   = (const float*)d_in[13];
  const float* Wih  = (const float*)d_in[14];
  const float* Whh  = (const float*)d_in[15];
  const float* bih  = (const float*)d_in[16];
  const float* bhh  = (const float*)d_in[17];

  float* wsf   = (float*)d_ws;
  float* gatew = wsf;                      // 32768 f
  float* shw   = wsf + 32768;              // 128 f
  float* xgw   = wsf + 32896;              // 524288 f  (ends at byte 2228736)
  unsigned short* memw = (unsigned short*)((char*)d_ws + 2228736); // 17.4 MB bf16
  const size_t WS_NEEDED = 2228736 + (size_t)8*128*AK*2;           // 19,595,776 B

  k_shared<<<128, 64, 0, stream>>>(WvB, WoW, WoB, shw);
  k_gate<<<dim3(8, 8), 256, 0, stream>>>(tar, tdw, tdb, gatew);

  if(ws_size >= WS_NEEDED){
    k_conv<<<128, 512, 0, stream>>>(img, gatew, cw, cb, shw, tar, memw);
    k_bias<<<2048, 256, 0, stream>>>(bih, bhh, xgw);
    k_gemm_mfma<<<dim3(32, 8, 4), 256, 0, stream>>>(memw, Wih, xgw);
  } else {
    k_gemm_old<<<dim3(4, 8, 8), 256, 0, stream>>>(img, gatew, cw, cb, shw, tar,
                                                  Wih, bih, bhh, xgw);
  }

  (void)hipFuncSetAttribute((const void*)k_lstm,
                            hipFuncAttributeMaxDynamicSharedMemorySize, 143360);
  k_lstm<<<8, 1024, 143360, stream>>>(xgw, Whh, (float*)d_out);
}

// Round 4
// 159.832 us; speedup vs baseline: 13.9222x; 2.0907x over previous
//
#include <hip/hip_runtime.h>

#define T_   16
#define B_   8
#define N_   8
#define H_   128
#define C_   32
#define HW_  256
#define TAR_ 145
#define G4H  512
#define MEMIN 8593
#define AK   8480   // padded K for MFMA path: 8192 conv + 128 shared + 145 tar + 15 zero
#define XGN  524288 // elements per xg buffer

typedef __attribute__((ext_vector_type(8))) short short8v;
typedef __attribute__((ext_vector_type(4))) float f32x4;
typedef __attribute__((ext_vector_type(4), aligned(4))) float f32x4u; // 4B-aligned vec load

__device__ __forceinline__ float bf2f(unsigned short u){
  return __uint_as_float(((unsigned int)u) << 16);
}
__device__ __forceinline__ unsigned short f2bf(float x){
  unsigned int b = __float_as_uint(x);
  return (unsigned short)((b + 0x7fffu + ((b >> 16) & 1u)) >> 16);
}
// pack two f32 -> two bf16 (round-nearest-ties-away) in one dword via v_perm_b32
__device__ __forceinline__ unsigned pkbf(float lo, float hi){
  return __builtin_amdgcn_perm(__float_as_uint(hi) + 0x8000u,
                               __float_as_uint(lo) + 0x8000u, 0x07060302u);
}
__device__ __forceinline__ float bflo(unsigned w){ return __uint_as_float(w << 16); }
__device__ __forceinline__ float bfhi(unsigned w){ return __uint_as_float(w & 0xffff0000u); }
__device__ __forceinline__ float sigf(float x){ return 1.f/(1.f + expf(-x)); }

// ---------------------------------------------------------------------------
// shared[h] = Wo_b[h] + sum_d Wv_b[d] * Wo_w[h,d]   (attention collapses)
// ---------------------------------------------------------------------------
__global__ void k_shared(const float* __restrict__ WvB, const float* __restrict__ WoW,
                         const float* __restrict__ WoB, float* __restrict__ sh){
  const int h = blockIdx.x, lane = threadIdx.x;
  float acc = 0.f;
  for(int d = lane; d < 896; d += 64) acc += WvB[d] * WoW[h*896 + d];
  for(int s = 32; s; s >>= 1) acc += __shfl_down(acc, s);
  if(lane == 0) sh[h] = acc + WoB[h];
}

// ---------------------------------------------------------------------------
// gate[tb,n,c] = sigmoid(td_b[n,c] + sum_{x<145} tar[tb,x]*td_w[n,c,x])
// ---------------------------------------------------------------------------
__global__ __launch_bounds__(256) void k_gate(const float* __restrict__ tar,
                                              const float* __restrict__ tdw,
                                              const float* __restrict__ tdb,
                                              float* __restrict__ gate){
  __shared__ float twS[32*145];
  __shared__ float taS[16*145];
  const int tb0 = blockIdx.x * 16, n = blockIdx.y, tid = threadIdx.x;
  for(int i = tid; i < 32*145; i += 256){
    int c = i / 145, x = i - c*145;
    twS[i] = tdw[(n*32 + c)*273 + x];
  }
  for(int i = tid; i < 16*145; i += 256)
    taS[i] = tar[tb0*145 + i];
  __syncthreads();
  for(int o = tid; o < 512; o += 256){
    int r = o >> 5, c = o & 31;
    float a = tdb[n*32 + c];
    const float* tr = &taS[r*145];
    const float* tw = &twS[c*145];
    for(int x = 0; x < 145; ++x) a += tr[x]*tw[x];
    gate[((tb0 + r)*N_ + n)*C_ + c] = 1.f/(1.f + expf(-a));
  }
}

// ---------------------------------------------------------------------------
// Build mem_bf16[n][tb][AK]: [0,8192) conv P, [8192,8320) shared,
// [8320,8465) tar, [8465,8480) zeros.  One block per tb; img staged once.
// ---------------------------------------------------------------------------
__global__ __launch_bounds__(512) void k_conv(
    const float* __restrict__ img, const float* __restrict__ gate,
    const float* __restrict__ cw, const float* __restrict__ cb,
    const float* __restrict__ sh, const float* __restrict__ tar,
    unsigned short* __restrict__ mem)
{
  __shared__ float imgS[8192];
  __shared__ float cwgS[1024];
  __shared__ float shS[128];
  __shared__ float tarS[160];
  const int tb = blockIdx.x, tid = threadIdx.x;
  for(int i = tid; i < 8192; i += 512)
    imgS[i] = img[(size_t)tb*8192 + i];
  if(tid < 128) shS[tid] = sh[tid];
  if(tid >= 128 && tid < 273) tarS[tid-128] = tar[tb*TAR_ + tid - 128];
  for(int n = 0; n < 8; ++n){
    __syncthreads();
    for(int i = tid; i < 1024; i += 512)
      cwgS[i] = cw[i] * gate[(tb*8 + n)*32 + (i & 31)];
    __syncthreads();
    unsigned short* mrow = mem + (size_t)(n*128 + tb)*AK;
    for(int q = 0; q < 4; ++q){
      const int idx = q*2048 + tid*4;
      const int d = idx >> 8, hw = idx & 255;
      const float bias = cb[d];
      float a0 = bias, a1 = bias, a2 = bias, a3 = bias;
      const float* cg = &cwgS[d*32];
      #pragma unroll
      for(int c = 0; c < 32; ++c){
        const f32x4 iv = *(const f32x4*)&imgS[c*256 + hw];
        const float w = cg[c];
        a0 += w*iv.x; a1 += w*iv.y; a2 += w*iv.z; a3 += w*iv.w;
      }
      ushort4 o;
      o.x = f2bf(a0); o.y = f2bf(a1); o.z = f2bf(a2); o.w = f2bf(a3);
      *(ushort4*)&mrow[idx] = o;
    }
    if(tid < 128)      mrow[8192 + tid]       = f2bf(shS[tid]);
    else if(tid < 273) mrow[8320 + tid - 128] = f2bf(tarS[tid - 128]);
    else if(tid < 288) mrow[8465 + tid - 273] = 0;
  }
}

// ---------------------------------------------------------------------------
// MFMA GEMM v2: grid (16 gt, 8 n, 4 ks), block 4 waves; block tile = 128 rows
// x 32 g; wave = 32 rows x 32 g (2x2 MFMA tiles).  K streamed from global;
// B f32 -> packed bf16 via v_perm (RN ties-away).  K-split writes 4 disjoint
// buffers (no atomics); lstm sums them.  C/D: col=lane&15,row=(lane>>4)*4+j.
// ---------------------------------------------------------------------------
__global__ __launch_bounds__(256) void k_gemm2(
    const unsigned short* __restrict__ mem, const float* __restrict__ Wih,
    float* __restrict__ xg4)
{
  const int gt = blockIdx.x, n = blockIdx.y, ks = blockIdx.z;
  const int wv = threadIdx.x >> 6, ln = threadIdx.x & 63;
  const int lr = ln & 15, lg = ln >> 4;
  const int g0 = gt*32;
  const int kbeg = (ks==0) ? 0 : (ks==1) ? 2144 : (ks==2) ? 4256 : 6368;
  const int kend = (ks==0) ? 2144 : (ks==1) ? 4256 : (ks==2) ? 6368 : 8480;
  const float* Bp0 = Wih + (size_t)(n*G4H + g0 + lr)*MEMIN + lg*8;
  const float* Bp1 = Bp0 + (size_t)16*MEMIN;
  const unsigned short* Ap0 = mem + (size_t)(n*128 + wv*32 + lr)*AK + lg*8;
  const unsigned short* Ap1 = Ap0 + (size_t)16*AK;
  f32x4 acc00 = {0.f,0.f,0.f,0.f}, acc01 = {0.f,0.f,0.f,0.f};
  f32x4 acc10 = {0.f,0.f,0.f,0.f}, acc11 = {0.f,0.f,0.f,0.f};
  for(int k = kbeg; k < kend; k += 32){
    const f32x4u bl0 = *(const f32x4u*)(Bp0 + k);
    const f32x4u bh0 = *(const f32x4u*)(Bp0 + k + 4);
    const f32x4u bl1 = *(const f32x4u*)(Bp1 + k);
    const f32x4u bh1 = *(const f32x4u*)(Bp1 + k + 4);
    short8v bf0, bf1;
    {
      unsigned* u0 = (unsigned*)&bf0;
      u0[0] = pkbf(bl0.x, bl0.y); u0[1] = pkbf(bl0.z, bl0.w);
      u0[2] = pkbf(bh0.x, bh0.y); u0[3] = pkbf(bh0.z, bh0.w);
      unsigned* u1 = (unsigned*)&bf1;
      u1[0] = pkbf(bl1.x, bl1.y); u1[1] = pkbf(bl1.z, bl1.w);
      u1[2] = pkbf(bh1.x, bh1.y); u1[3] = pkbf(bh1.z, bh1.w);
    }
    const short8v a0 = *(const short8v*)(Ap0 + k);
    const short8v a1 = *(const short8v*)(Ap1 + k);
    acc00 = __builtin_amdgcn_mfma_f32_16x16x32_bf16(a0, bf0, acc00, 0, 0, 0);
    acc01 = __builtin_amdgcn_mfma_f32_16x16x32_bf16(a0, bf1, acc01, 0, 0, 0);
    acc10 = __builtin_amdgcn_mfma_f32_16x16x32_bf16(a1, bf0, acc10, 0, 0, 0);
    acc11 = __builtin_amdgcn_mfma_f32_16x16x32_bf16(a1, bf1, acc11, 0, 0, 0);
  }
  float* dst = xg4 + (size_t)ks*XGN;
  const int c0 = g0 + lr, c1 = g0 + 16 + lr;
  const int r0 = wv*32 + lg*4, r1 = r0 + 16;
  #pragma unroll
  for(int j = 0; j < 4; ++j){
    dst[(size_t)((r0 + j)*8 + n)*G4H + c0] = acc00[j];
    dst[(size_t)((r0 + j)*8 + n)*G4H + c1] = acc01[j];
    dst[(size_t)((r1 + j)*8 + n)*G4H + c0] = acc10[j];
    dst[(size_t)((r1 + j)*8 + n)*G4H + c1] = acc11[j];
  }
}

// ---------------------------------------------------------------------------
// LSTM v2: 64 blocks = (b,n) pairs, 512 threads = gate-row g.  Whh row held
// packed-bf16 in 64 VGPRs (loaded once).  Per step: sum 4 K-split xg buffers
// + bias, dot over broadcast h (LDS), activations by threads<128.
// ---------------------------------------------------------------------------
__global__ __launch_bounds__(512) void k_lstm2(
    const float* __restrict__ xg4, const float* __restrict__ Whh,
    const float* __restrict__ bih, const float* __restrict__ bhh,
    float* __restrict__ out)
{
  __shared__ float hS[128];
  __shared__ float preS[512];
  const int bn = blockIdx.x;
  const int n = bn & 7, b = bn >> 3;
  const int g = threadIdx.x;

  unsigned wr[64];
  const float* wrow = Whh + (size_t)(n*G4H + g)*H_;
  #pragma unroll
  for(int i = 0; i < 32; ++i){
    const f32x4 w = *(const f32x4*)(wrow + i*4);
    wr[2*i]   = pkbf(w.x, w.y);
    wr[2*i+1] = pkbf(w.z, w.w);
  }
  const float bias = bih[n*G4H + g] + bhh[n*G4H + g];
  if(g < 128) hS[g] = 0.f;
  float cc = 0.f;
  __syncthreads();

  for(int t = 0; t < 16; ++t){
    const size_t xb = (size_t)((t*8 + b)*8 + n)*G4H + g;
    float acc = bias + xg4[xb] + xg4[xb + XGN] + xg4[xb + 2*XGN] + xg4[xb + 3*XGN];
    #pragma unroll
    for(int q = 0; q < 32; ++q){
      const f32x4 hv = *(const f32x4*)&hS[q*4];
      const unsigned w0 = wr[2*q], w1 = wr[2*q+1];
      acc += hv.x*bflo(w0) + hv.y*bfhi(w0) + hv.z*bflo(w1) + hv.w*bfhi(w1);
    }
    preS[g] = acc;
    __syncthreads();
    if(g < 128){
      const float iv = sigf(preS[g]);
      const float fv = sigf(preS[128 + g]);
      const float gv = tanhf(preS[256 + g]);
      const float ov = sigf(preS[384 + g]);
      cc = fv*cc + iv*gv;
      const float hn = ov*tanhf(cc);
      hS[g] = hn;
      out[(t*8 + b)*1024 + n*128 + g] = hn;
      if(t == 15){
        out[131072 + (b*8 + n)*128 + g] = hn;   // hT
        out[139264 + (b*8 + n)*128 + g] = cc;   // cT
      }
    }
    __syncthreads();
  }
}

// ---------------------------------------------------------------------------
// Tier-B fallbacks (round-3 verified): bias init + atomic MFMA gemm + old lstm
// ---------------------------------------------------------------------------
__global__ __launch_bounds__(256) void k_bias(const float* __restrict__ bih,
                                              const float* __restrict__ bhh,
                                              float* __restrict__ xg){
  const int i = blockIdx.x*256 + threadIdx.x;
  const int ng = ((i >> 9) & 7)*512 + (i & 511);
  xg[i] = bih[ng] + bhh[ng];
}

__global__ __launch_bounds__(256) void k_gemm_mfma(
    const unsigned short* __restrict__ mem, const float* __restrict__ Wih,
    float* __restrict__ xg)
{
  const int gt = blockIdx.x, n = blockIdx.y, ks = blockIdx.z;
  const int wv = threadIdx.x >> 6, ln = threadIdx.x & 63;
  const int lr = ln & 15, lg = ln >> 4;
  const int g0 = gt*16;
  const int kbeg = (ks==0) ? 0 : (ks==1) ? 2144 : (ks==2) ? 4256 : 6368;
  const int kend = (ks==0) ? 2144 : (ks==1) ? 4256 : (ks==2) ? 6368 : 8480;
  const float* Bp = Wih + (size_t)(n*G4H + g0 + lr)*MEMIN + lg*8;
  const unsigned short* Ap = mem + (size_t)(n*128 + wv*32 + lr)*AK + lg*8;
  f32x4 acc0 = {0.f,0.f,0.f,0.f};
  f32x4 acc1 = {0.f,0.f,0.f,0.f};
  #pragma unroll 2
  for(int k = kbeg; k < kend; k += 32){
    const f32x4u blo = *(const f32x4u*)(Bp + k);
    const f32x4u bhi = *(const f32x4u*)(Bp + k + 4);
    short8v bf;
    unsigned* bu = (unsigned*)&bf;
    bu[0] = pkbf(blo.x, blo.y); bu[1] = pkbf(blo.z, blo.w);
    bu[2] = pkbf(bhi.x, bhi.y); bu[3] = pkbf(bhi.z, bhi.w);
    const short8v a0 = *(const short8v*)(Ap + k);
    const short8v a1 = *(const short8v*)(Ap + (size_t)16*AK + k);
    acc0 = __builtin_amdgcn_mfma_f32_16x16x32_bf16(a0, bf, acc0, 0, 0, 0);
    acc1 = __builtin_amdgcn_mfma_f32_16x16x32_bf16(a1, bf, acc1, 0, 0, 0);
  }
  const int col = g0 + lr;
  const int r0  = wv*32 + lg*4;
  #pragma unroll
  for(int j = 0; j < 4; ++j){
    atomicAdd(&xg[(size_t)((r0 + j)*8 + n)*G4H + col],      acc0[j]);
    atomicAdd(&xg[(size_t)((r0 + 16 + j)*8 + n)*G4H + col], acc1[j]);
  }
}

__global__ __launch_bounds__(1024) void k_lstm(
    const float* __restrict__ xg, const float* __restrict__ Whh,
    float* __restrict__ out)
{
  extern __shared__ char smem[];
  unsigned short* Wl = (unsigned short*)smem;
  float* hS = (float*)(smem + 512*136*sizeof(unsigned short));

  const int n = blockIdx.x, tid = threadIdx.x;
  for(int i = tid; i < 512*128; i += 1024){
    int g = i >> 7, k = i & 127;
    Wl[g*136 + k] = f2bf(Whh[n*512*128 + i]);
  }
  hS[tid] = 0.f;
  const int h = tid >> 3, b = tid & 7;
  float cc = 0.f;
  __syncthreads();

  for(int t = 0; t < 16; ++t){
    const long xbase = ((long)((t*8 + b)*8 + n))*G4H + h;
    float g0 = xg[xbase + 0*128];
    float g1 = xg[xbase + 1*128];
    float g2 = xg[xbase + 2*128];
    float g3 = xg[xbase + 3*128];
    const float* hr = &hS[b*128];
    const unsigned short* w0 = &Wl[(0*128 + h)*136];
    const unsigned short* w1 = &Wl[(1*128 + h)*136];
    const unsigned short* w2 = &Wl[(2*128 + h)*136];
    const unsigned short* w3 = &Wl[(3*128 + h)*136];
    for(int k = 0; k < 128; k += 4){
      const float4 hv = *(const float4*)&hr[k];
      const ushort4 a0 = *(const ushort4*)&w0[k];
      const ushort4 a1 = *(const ushort4*)&w1[k];
      const ushort4 a2 = *(const ushort4*)&w2[k];
      const ushort4 a3 = *(const ushort4*)&w3[k];
      g0 += hv.x*bf2f(a0.x) + hv.y*bf2f(a0.y) + hv.z*bf2f(a0.z) + hv.w*bf2f(a0.w);
      g1 += hv.x*bf2f(a1.x) + hv.y*bf2f(a1.y) + hv.z*bf2f(a1.z) + hv.w*bf2f(a1.w);
      g2 += hv.x*bf2f(a2.x) + hv.y*bf2f(a2.y) + hv.z*bf2f(a2.z) + hv.w*bf2f(a2.w);
      g3 += hv.x*bf2f(a3.x) + hv.y*bf2f(a3.y) + hv.z*bf2f(a3.z) + hv.w*bf2f(a3.w);
    }
    const float iv = sigf(g0);
    const float fv = sigf(g1);
    const float gv = tanhf(g2);
    const float ov = sigf(g3);
    cc = fv*cc + iv*gv;
    const float hn = ov * tanhf(cc);
    __syncthreads();
    hS[b*128 + h] = hn;
    out[(t*8 + b)*1024 + n*128 + h] = hn;
    if(t == 15){
      out[131072 + (b*8 + n)*128 + h] = hn;
      out[139264 + (b*8 + n)*128 + h] = cc;
    }
    __syncthreads();
  }
}

// ---------------------------------------------------------------------------
// Tier-C fallback (round-2 verified, no extra ws): fused VALU gemm
// ---------------------------------------------------------------------------
__global__ __launch_bounds__(256) void k_gemm_old(
    const float* __restrict__ img, const float* __restrict__ gate,
    const float* __restrict__ cw, const float* __restrict__ cb,
    const float* __restrict__ sh, const float* __restrict__ tar,
    const float* __restrict__ Wih, const float* __restrict__ bih,
    const float* __restrict__ bhh, float* __restrict__ xg)
{
  __shared__ __align__(16) float imgS[16*545];
  __shared__ __align__(16) float WtS[16*132];
  __shared__ float PS[16*17];
  __shared__ float gateS[16*32];
  __shared__ float cw2S[16*32];
  __shared__ float cwS[32*32];
  __shared__ float cbS[32];
  __shared__ float shS[128];
  __shared__ float tarS[16*145];

  const int tid = threadIdx.x;
  const int g0  = blockIdx.x * 128;
  const int tb0 = blockIdx.y * 16;
  const int n   = blockIdx.z;
  const int gth = tid & 31;
  const int rth = tid >> 5;
  const long wbase = (long)(n*G4H + g0) * MEMIN;

  for(int i = tid; i < 16*32; i += 256){
    int r = i >> 5, c = i & 31;
    gateS[i] = gate[((tb0 + r)*N_ + n)*C_ + c];
  }
  for(int i = tid; i < 32*32; i += 256) cwS[i] = cw[i];
  if(tid < 32)  cbS[tid] = cb[tid];
  if(tid < 128) shS[tid] = sh[tid];
  for(int i = tid; i < 16*TAR_; i += 256)
    tarS[i] = tar[tb0*TAR_ + i];

  float acc0[4] = {0,0,0,0}, acc1[4] = {0,0,0,0};

  for(int s = 0; s < 16; ++s){
    __syncthreads();
    for(int i = tid; i < 8192; i += 256){
      int j = i & 15, c = (i >> 4) & 31, r = i >> 9;
      imgS[r*545 + c*17 + j] = img[((tb0 + r)*C_ + c)*HW_ + s*16 + j];
    }
    for(int d = 0; d < 32; ++d){
      __syncthreads();
      for(int i = tid; i < 2048; i += 256){
        int g = i >> 4, j = i & 15;
        WtS[j*132 + g] = Wih[wbase + (long)g*MEMIN + d*HW_ + s*16 + j];
      }
      for(int i = tid; i < 512; i += 256)
        cw2S[i] = gateS[i] * cwS[d*32 + (i & 31)];
      __syncthreads();
      {
        int j = tid & 15, r = tid >> 4;
        float a = cbS[d];
        const float* c2 = &cw2S[r*32];
        const float* im = &imgS[r*545 + j];
        #pragma unroll
        for(int c = 0; c < 32; ++c) a += c2[c] * im[c*17];
        PS[j*17 + r] = a;
      }
      __syncthreads();
      #pragma unroll
      for(int j = 0; j < 16; ++j){
        const float4 w = *(const float4*)&WtS[j*132 + (gth << 2)];
        const float p0 = PS[j*17 + (rth << 1)];
        const float p1 = PS[j*17 + (rth << 1) + 1];
        acc0[0] += p0*w.x; acc0[1] += p0*w.y; acc0[2] += p0*w.z; acc0[3] += p0*w.w;
        acc1[0] += p1*w.x; acc1[1] += p1*w.y; acc1[2] += p1*w.z; acc1[3] += p1*w.w;
      }
    }
  }
  {
    float ta[4] = {0,0,0,0};
    for(int kc = 0; kc < 8; ++kc){
      __syncthreads();
      for(int i = tid; i < 2048; i += 256){
        int g = i >> 4, j = i & 15;
        WtS[j*132 + g] = Wih[wbase + (long)g*MEMIN + 8192 + kc*16 + j];
      }
      __syncthreads();
      #pragma unroll
      for(int j = 0; j < 16; ++j){
        const float4 w = *(const float4*)&WtS[j*132 + (gth << 2)];
        const float sv = shS[kc*16 + j];
        ta[0] += sv*w.x; ta[1] += sv*w.y; ta[2] += sv*w.z; ta[3] += sv*w.w;
      }
    }
    acc0[0] += ta[0]; acc0[1] += ta[1]; acc0[2] += ta[2]; acc0[3] += ta[3];
    acc1[0] += ta[0]; acc1[1] += ta[1]; acc1[2] += ta[2]; acc1[3] += ta[3];
  }
  for(int kc = 0; kc < 10; ++kc){
    const int kendl = (kc == 9) ? 1 : 16;
    __syncthreads();
    for(int i = tid; i < 2048; i += 256){
      int g = i >> 4, j = i & 15;
      if(j < kendl)
        WtS[j*132 + g] = Wih[wbase + (long)g*MEMIN + 8320 + kc*16 + j];
    }
    __syncthreads();
    for(int j = 0; j < kendl; ++j){
      const float4 w = *(const float4*)&WtS[j*132 + (gth << 2)];
      const float p0 = tarS[(rth << 1)*TAR_ + kc*16 + j];
      const float p1 = tarS[((rth << 1) + 1)*TAR_ + kc*16 + j];
      acc0[0] += p0*w.x; acc0[1] += p0*w.y; acc0[2] += p0*w.z; acc0[3] += p0*w.w;
      acc1[0] += p1*w.x; acc1[1] += p1*w.y; acc1[2] += p1*w.z; acc1[3] += p1*w.w;
    }
  }
  {
    const int gg = g0 + (gth << 2);
    const float b0 = bih[n*G4H + gg + 0] + bhh[n*G4H + gg + 0];
    const float b1 = bih[n*G4H + gg + 1] + bhh[n*G4H + gg + 1];
    const float b2 = bih[n*G4H + gg + 2] + bhh[n*G4H + gg + 2];
    const float b3 = bih[n*G4H + gg + 3] + bhh[n*G4H + gg + 3];
    const int row = tb0 + (rth << 1);
    float4 o0 = make_float4(acc0[0]+b0, acc0[1]+b1, acc0[2]+b2, acc0[3]+b3);
    *(float4*)&xg[((long)(row*N_ + n))*G4H + gg] = o0;
    float4 o1 = make_float4(acc1[0]+b0, acc1[1]+b1, acc1[2]+b2, acc1[3]+b3);
    *(float4*)&xg[((long)((row + 1)*N_ + n))*G4H + gg] = o1;
  }
}

// ---------------------------------------------------------------------------
extern "C" void kernel_launch(void* const* d_in, const int* in_sizes, int n_in,
                              void* d_out, int out_size, void* d_ws, size_t ws_size,
                              hipStream_t stream)
{
  (void)in_sizes; (void)n_in; (void)out_size;
  const float* img  = (const float*)d_in[0];
  const float* tar  = (const float*)d_in[1];
  const float* WvB  = (const float*)d_in[7];
  const float* WoW  = (const float*)d_in[8];
  const float* WoB  = (const float*)d_in[9];
  const float* tdw  = (const float*)d_in[10];
  const float* tdb  = (const float*)d_in[11];
  const float* cw   = (const float*)d_in[12];
  const float* cb   = (const float*)d_in[13];
  const float* Wih  = (const float*)d_in[14];
  const float* Whh  = (const float*)d_in[15];
  const float* bih  = (const float*)d_in[16];
  const float* bhh  = (const float*)d_in[17];

  float* wsf   = (float*)d_ws;
  float* gatew = wsf;                       // 32768 f
  float* shw   = wsf + 32768;               // 128 f

  // Tier A layout: xg4 @ f32[32896..2130048) (4 x 524288), mem @ byte 8520192
  float* xg4w = wsf + 32896;
  unsigned short* memA = (unsigned short*)((char*)d_ws + 8520192);
  const size_t WS_A = 8520192 + (size_t)8*128*AK*2;          // 25,887,232 B

  // Tier B layout (round-3): xg @ f32[32896..557184), mem @ byte 2228736
  float* xgB = wsf + 32896;
  unsigned short* memB = (unsigned short*)((char*)d_ws + 2228736);
  const size_t WS_B = 2228736 + (size_t)8*128*AK*2;          // 19,595,776 B

  k_shared<<<128, 64, 0, stream>>>(WvB, WoW, WoB, shw);
  k_gate<<<dim3(8, 8), 256, 0, stream>>>(tar, tdw, tdb, gatew);

  if(ws_size >= WS_A){
    k_conv<<<128, 512, 0, stream>>>(img, gatew, cw, cb, shw, tar, memA);
    k_gemm2<<<dim3(16, 8, 4), 256, 0, stream>>>(memA, Wih, xg4w);
    k_lstm2<<<64, 512, 0, stream>>>(xg4w, Whh, bih, bhh, (float*)d_out);
  } else if(ws_size >= WS_B){
    k_conv<<<128, 512, 0, stream>>>(img, gatew, cw, cb, shw, tar, memB);
    k_bias<<<2048, 256, 0, stream>>>(bih, bhh, xgB);
    k_gemm_mfma<<<dim3(32, 8, 4), 256, 0, stream>>>(memB, Wih, xgB);
    (void)hipFuncSetAttribute((const void*)k_lstm,
                              hipFuncAttributeMaxDynamicSharedMemorySize, 143360);
    k_lstm<<<8, 1024, 143360, stream>>>(xgB, Whh, (float*)d_out);
  } else {
    k_gemm_old<<<dim3(4, 8, 8), 256, 0, stream>>>(img, gatew, cw, cb, shw, tar,
                                                  Wih, bih, bhh, xgB);
    (void)hipFuncSetAttribute((const void*)k_lstm,
                              hipFuncAttributeMaxDynamicSharedMemorySize, 143360);
    k_lstm<<<8, 1024, 143360, stream>>>(xgB, Whh, (float*)d_out);
  }
}